// Round 15
// baseline (62.898 us; speedup 1.0000x reference)
//
#include <hip/hip_runtime.h>
#include <hip/hip_bf16.h>
#include <stdint.h>

#define N_TOK   4096
#define TOPK    2
#define NSORT   (N_TOK * TOPK)   // 8192
#define NEXP    8
#define DIM     1024

#define BM 128
#define BN 64
#define BK 64

typedef __attribute__((ext_vector_type(8))) short bfrag;    // 8 bf16 = 4 VGPR (MFMA A/B operand)
typedef __attribute__((ext_vector_type(4))) float f32x4;    // MFMA C/D

static __device__ __forceinline__ unsigned short f2bf(float f) {
  __hip_bfloat16 h = __float2bfloat16(f);
  return __builtin_bit_cast(unsigned short, h);
}
static __device__ __forceinline__ float bf2f(unsigned short u) {
  unsigned int v = ((unsigned int)u) << 16;
  return __builtin_bit_cast(float, v);
}

// async global->LDS, 16B per lane; lds base must be wave-uniform (HW writes base + lane*16)
static __device__ __forceinline__ void gload16(void* lds_base, const void* gsrc) {
  __builtin_amdgcn_global_load_lds(
      (const __attribute__((address_space(1))) void*)gsrc,
      (__attribute__((address_space(3))) void*)lds_base, 16, 0, 0);
}

// ---------------- kernel 1: straight cast x fp32 -> bf16 (token order; no gather) -------
__global__ __launch_bounds__(256) void k_prep(
    const float* __restrict__ x, unsigned short* __restrict__ xb, float* __restrict__ zbuf)
{
  const size_t i = ((size_t)blockIdx.x * 256 + threadIdx.x) * 8;   // 8 floats/thread
  float4 a = *(const float4*)(x + i);
  float4 b = *(const float4*)(x + i + 4);
  ushort4 oa, ob;
  oa.x = f2bf(a.x); oa.y = f2bf(a.y); oa.z = f2bf(a.z); oa.w = f2bf(a.w);
  ob.x = f2bf(b.x); ob.y = f2bf(b.y); ob.z = f2bf(b.z); ob.w = f2bf(b.w);
  *(ushort4*)(xb + i) = oa;
  *(ushort4*)(xb + i + 4) = ob;
  if (blockIdx.x == 0) {                     // 4KB zero page (masked staging; koff<2KB +16B)
    zbuf[threadIdx.x] = 0.f; zbuf[256 + threadIdx.x] = 0.f;
    zbuf[512 + threadIdx.x] = 0.f; zbuf[768 + threadIdx.x] = 0.f;
  }
}

// ---------------- kernel 2: W [e][k][n] fp32 -> WT [e][n][k] bf16 (LDS-tiled transpose) ---
__global__ __launch_bounds__(256) void k_transp_w(
    const float* __restrict__ W, unsigned short* __restrict__ WT)
{
  __shared__ float tile[64][65];
  const int nb = blockIdx.x;   // 16
  const int kb = blockIdx.y;   // 16
  const int e  = blockIdx.z;   // 8
  const int t = threadIdx.x;
  const float* src = W + (((size_t)e * DIM) + (size_t)kb * 64) * DIM + nb * 64;
  #pragma unroll
  for (int p = 0; p < 4; ++p) {
    int q = p * 256 + t;       // 0..1023 float4-units
    int i = q >> 4;            // k-row 0..63
    int j4 = q & 15;           // float4 within row
    float4 v = *(const float4*)(src + (size_t)i * DIM + j4 * 4);
    tile[i][j4 * 4 + 0] = v.x; tile[i][j4 * 4 + 1] = v.y;
    tile[i][j4 * 4 + 2] = v.z; tile[i][j4 * 4 + 3] = v.w;
  }
  __syncthreads();
  unsigned short* dst = WT + (((size_t)e * DIM) + (size_t)nb * 64) * DIM + kb * 64;
  #pragma unroll
  for (int p = 0; p < 4; ++p) {
    int q = p * 256 + t;
    int j = q >> 4;            // n-row 0..63
    int i4 = q & 15;           // k float4
    ushort4 o;
    o.x = f2bf(tile[i4 * 4 + 0][j]);
    o.y = f2bf(tile[i4 * 4 + 1][j]);
    o.z = f2bf(tile[i4 * 4 + 2][j]);
    o.w = f2bf(tile[i4 * 4 + 3][j]);
    *(ushort4*)(dst + (size_t)j * DIM + i4 * 4) = o;
  }
}

// -- kernel 3: grouped GEMM, r7 geometry (128x64, BK=64, 25KB LDS) + split-K x2 ----------
// grid 2048 -> 6 resident blocks/CU (LDS-capped) + queue; the r7 2-barrier loop unchanged.
__global__ __launch_bounds__(256, 6) void k_moe_gemm(
    const unsigned short* __restrict__ xb,   // [N_TOK][DIM] bf16 (token order)
    const unsigned short* __restrict__ WT,   // [NEXP][DIM n][DIM k] bf16
    const int* __restrict__ sei, const int* __restrict__ ssi, const int* __restrict__ kp,
    const float* __restrict__ zbuf,
    unsigned short* __restrict__ p0,         // [NSORT][DIM] bf16 partial, k-half 0
    unsigned short* __restrict__ p1)         // [NSORT][DIM] bf16 partial, k-half 1
{
  __shared__ unsigned short lA[BM * BK];   // 16 KB
  __shared__ unsigned short lB[BN * BK];   // 8 KB
  __shared__ int s_sei[BM];
  __shared__ int s_ssi[BM];
  __shared__ int s_tok[BM];

  // XCD-aware bijective swizzle (nwg=2048, 2048%8==0): contiguous 256-block chunk per XCD;
  // (ct,half) fastest so the 32 blocks sharing one A row-panel stay in one XCD's L2.
  const int swz = (blockIdx.x & 7) * 256 + (blockIdx.x >> 3);
  const int rt   = swz >> 5;           // 0..63 row tile
  const int rem  = swz & 31;
  const int ct   = rem >> 1;           // 0..15 col tile
  const int half = rem & 1;            // k-half
  const int t = threadIdx.x;
  const int lane = t & 63;
  const int w = t >> 6;                // 4 waves, 2M x 2N (64x32 tile each)
  const int wr = w >> 1;
  const int wc = w & 1;
  const int kk = kp[0];

  if (t < BM) {
    const int si = ssi[rt * BM + t];
    s_sei[t] = sei[rt * BM + t];
    s_ssi[t] = si;
    s_tok[t] = si / kk;                // source token for A-row indirection (no gather pass)
  }
  __syncthreads();

  const int e0 = s_sei[0];
  const int e1 = s_sei[BM - 1];
  const int nsteps = (e1 - e0 + 1) * (DIM / BK / 2);   // 8 K-steps per expert (half K-range)

  f32x4 acc[4][2];
  #pragma unroll
  for (int m = 0; m < 4; ++m)
    #pragma unroll
    for (int n = 0; n < 2; ++n)
      acc[m][n] = (f32x4){0.f, 0.f, 0.f, 0.f};

  const int g = lane >> 4;
  const int r = lane & 15;

  // staging geometry (rule 21: linear LDS dest, inverse-swizzled global source)
  // A: 16 chunks of 1KB, wave owns 4w..4w+3;  B: 8 chunks, wave owns 2w..2w+1
  int rA[4], kA[4], rB[2], kB[2];
  #pragma unroll
  for (int i = 0; i < 4; ++i) {
    int o = (4 * w + i) * 1024 + lane * 16;
    int osw = o ^ (((o >> 7) & 7) << 4);
    rA[i] = osw >> 7; kA[i] = osw & 127;
  }
  #pragma unroll
  for (int i = 0; i < 2; ++i) {
    int o = (2 * w + i) * 1024 + lane * 16;
    int osw = o ^ (((o >> 7) & 7) << 4);
    rB[i] = osw >> 7; kB[i] = osw & 127;   // n-row 0..63
  }

  // per-expert hoisted source bases (per-lane); masked A rows point at the 4KB zero page
  const char *ap[4], *bp[2];
  int ecur = 0x7fffffff;
  auto setup = [&](int e) {
    #pragma unroll
    for (int i = 0; i < 4; ++i)
      ap[i] = (s_sei[rA[i]] == e)
          ? (const char*)(xb + (size_t)s_tok[rA[i]] * DIM) + kA[i] : (const char*)zbuf;
    #pragma unroll
    for (int i = 0; i < 2; ++i)
      bp[i] = (const char*)(WT + (((size_t)e * DIM) + ct * BN + rB[i]) * DIM) + kB[i];
  };
  auto stage = [&](int s) {
    const int e = e0 + (s >> 3);
    if (e != ecur) { ecur = e; setup(e); }   // wave-uniform, fires ~1.1x per block
    const int koff = half * 1024 + (s & 7) * 128;   // bytes along k (4KB zero page covers)
    #pragma unroll
    for (int i = 0; i < 4; ++i)
      gload16((char*)lA + (4 * w + i) * 1024, ap[i] + koff);
    #pragma unroll
    for (int i = 0; i < 2; ++i)
      gload16((char*)lB + (2 * w + i) * 1024, bp[i] + koff);
  };

  for (int s = 0; s < nsteps; ++s) {
    stage(s);
    __syncthreads();   // vmcnt(0) drain + barrier (6 resident blocks/CU hide the drain)
    #pragma unroll
    for (int kh = 0; kh < 2; ++kh) {
      const int kbyte = (kh * 32 + 8 * g) * 2;   // same k-slot for A and B (positional symmetry)
      bfrag af[4], bfv[2];
      #pragma unroll
      for (int m = 0; m < 4; ++m) {
        const int row = wr * 64 + m * 16 + r;
        int o = (row << 7) + kbyte;
        o ^= ((row & 7) << 4);
        af[m] = *(const bfrag*)((const char*)lA + o);
      }
      #pragma unroll
      for (int n = 0; n < 2; ++n) {
        const int nn = wc * 32 + n * 16 + r;
        int o = (nn << 7) + kbyte;
        o ^= ((nn & 7) << 4);
        bfv[n] = *(const bfrag*)((const char*)lB + o);
      }
      #pragma unroll
      for (int m = 0; m < 4; ++m)
        #pragma unroll
        for (int n = 0; n < 2; ++n)
          acc[m][n] = __builtin_amdgcn_mfma_f32_16x16x32_bf16(af[m], bfv[n], acc[m][n], 0, 0, 0);
    }
    __syncthreads();   // compute done before next stage overwrites LDS
  }

  // epilogue: C/D map col = lane&15, row = (lane>>4)*4 + reg; scatter rows by ssi (bf16)
  unsigned short* pd = half ? p1 : p0;
  #pragma unroll
  for (int m = 0; m < 4; ++m) {
    #pragma unroll
    for (int q = 0; q < 4; ++q) {
      const int rl = wr * 64 + m * 16 + g * 4 + q;
      const int orow = s_ssi[rl];
      unsigned short* od = pd + (size_t)orow * DIM + ct * BN + wc * 32 + r;
      #pragma unroll
      for (int n = 0; n < 2; ++n)
        od[n * 16] = f2bf(acc[m][n][q]);
    }
  }
}

// ---------------- kernel 4: gate-weighted combine of the two k-half partials ------------
__global__ __launch_bounds__(256) void k_combine(
    const unsigned short* __restrict__ p0, const unsigned short* __restrict__ p1,
    const float* __restrict__ gates, const int* __restrict__ kp,
    float* __restrict__ out)
{
  const int tk = blockIdx.x;     // token
  const int t = threadIdx.x;     // 256 threads x 4 floats
  const int kk = kp[0];
  float4 o = {0.f, 0.f, 0.f, 0.f};
  for (int s = 0; s < kk; ++s) {
    const float gte = gates[tk * kk + s];
    const size_t base = ((size_t)tk * kk + s) * DIM;
    ushort4 a = ((const ushort4*)(p0 + base))[t];
    ushort4 b = ((const ushort4*)(p1 + base))[t];
    o.x += gte * (bf2f(a.x) + bf2f(b.x));
    o.y += gte * (bf2f(a.y) + bf2f(b.y));
    o.z += gte * (bf2f(a.z) + bf2f(b.z));
    o.w += gte * (bf2f(a.w) + bf2f(b.w));
  }
  ((float4*)(out + (size_t)tk * DIM))[t] = o;
}

extern "C" void kernel_launch(void* const* d_in, const int* in_sizes, int n_in,
                              void* d_out, int out_size, void* d_ws, size_t ws_size,
                              hipStream_t stream)
{
  const float* x     = (const float*)d_in[0];
  const float* W     = (const float*)d_in[1];
  const float* gates = (const float*)d_in[2];
  const int* kp      = (const int*)d_in[3];
  const int* sei     = (const int*)d_in[4];
  const int* ssi     = (const int*)d_in[5];
  // d_in[6] padded_block_idxs, d_in[7] expert_offsets: not needed (masked pass loop)

  const size_t MB = 1024 * 1024;
  if (ws_size < 56 * MB + 8192) return;   // 56MB scratch + 4KB zero page

  char* ws = (char*)d_ws;
  unsigned short* xb = (unsigned short*)(ws);              // 8  MB: bf16 x (token order)
  unsigned short* WT = (unsigned short*)(ws + 8 * MB);     // 16 MB: bf16 W^T
  unsigned short* p0 = (unsigned short*)(ws + 24 * MB);    // 16 MB: partial, k-half 0
  unsigned short* p1 = (unsigned short*)(ws + 40 * MB);    // 16 MB: partial, k-half 1
  float* zbuf        = (float*)(ws + 56 * MB);             // 4 KB zero page

  k_prep<<<N_TOK * DIM / (256 * 8), 256, 0, stream>>>(x, xb, zbuf);
  k_transp_w<<<dim3(16, 16, 8), 256, 0, stream>>>(W, WT);
  k_moe_gemm<<<(NSORT / BM) * (DIM / BN) * 2, 256, 0, stream>>>(
      xb, WT, sei, ssi, kp, zbuf, p0, p1);
  k_combine<<<N_TOK, 256, 0, stream>>>(p0, p1, gates, kp, (float*)d_out);
}

// Round 17
// 54.282 us; speedup vs baseline: 1.1587x; 1.1587x over previous
//
#include <hip/hip_runtime.h>
#include <hip/hip_bf16.h>
#include <stdint.h>

#define N_TOK   4096
#define TOPK    2
#define NSORT   (N_TOK * TOPK)   // 8192
#define NEXP    8
#define DIM     1024

#define BM 128
#define BN 64
#define BK 64
#define MAXTILES 72              // sum_e ceil(cnt_e/128) <= 64 + 7; padded to 72

typedef __attribute__((ext_vector_type(8))) short bfrag;    // 8 bf16 = 4 VGPR (MFMA A/B operand)
typedef __attribute__((ext_vector_type(4))) float f32x4;    // MFMA C/D

static __device__ __forceinline__ unsigned short f2bf(float f) {
  __hip_bfloat16 h = __float2bfloat16(f);
  return __builtin_bit_cast(unsigned short, h);
}
static __device__ __forceinline__ float bf2f(unsigned short u) {
  unsigned int v = ((unsigned int)u) << 16;
  return __builtin_bit_cast(float, v);
}

// async global->LDS, 16B per lane; lds base must be wave-uniform (HW writes base + lane*16)
static __device__ __forceinline__ void gload16(void* lds_base, const void* gsrc) {
  __builtin_amdgcn_global_load_lds(
      (const __attribute__((address_space(1))) void*)gsrc,
      (__attribute__((address_space(3))) void*)lds_base, 16, 0, 0);
}

// -- kernel 1: cast x fp32 -> bf16 (token order); block 0 also builds tile table + zero page
__global__ __launch_bounds__(256) void k_prep(
    const float* __restrict__ x, const int* __restrict__ eoff,
    unsigned short* __restrict__ xb, float* __restrict__ zbuf, int* __restrict__ tbl)
{
  const size_t i = ((size_t)blockIdx.x * 256 + threadIdx.x) * 8;   // 8 floats/thread
  float4 a = *(const float4*)(x + i);
  float4 b = *(const float4*)(x + i + 4);
  ushort4 oa, ob;
  oa.x = f2bf(a.x); oa.y = f2bf(a.y); oa.z = f2bf(a.z); oa.w = f2bf(a.w);
  ob.x = f2bf(b.x); ob.y = f2bf(b.y); ob.z = f2bf(b.z); ob.w = f2bf(b.w);
  *(ushort4*)(xb + i) = oa;
  *(ushort4*)(xb + i + 4) = ob;
  if (blockIdx.x == 0) {                     // 4KB zero page (masked staging)
    zbuf[threadIdx.x] = 0.f; zbuf[256 + threadIdx.x] = 0.f;
    zbuf[512 + threadIdx.x] = 0.f; zbuf[768 + threadIdx.x] = 0.f;
    if (threadIdx.x == 0) {                  // expert-aligned tile table (single thread, 72 it)
      int ti = 0, prev = 0;
      for (int e = 0; e < NEXP; ++e) {
        const int end = eoff[e];
        for (int r0 = prev; r0 < end; r0 += BM) {
          tbl[ti * 2 + 0] = e;
          tbl[ti * 2 + 1] = r0;
          ++ti;
        }
        prev = end;
      }
      for (; ti < MAXTILES; ++ti) { tbl[ti * 2 + 0] = -1; tbl[ti * 2 + 1] = 0; }
    }
  }
}

// ---------------- kernel 2: W [e][k][n] fp32 -> WT [e][n][k] bf16 (LDS-tiled transpose) ---
__global__ __launch_bounds__(256) void k_transp_w(
    const float* __restrict__ W, unsigned short* __restrict__ WT)
{
  __shared__ float tile[64][65];
  const int nb = blockIdx.x;   // 16
  const int kb = blockIdx.y;   // 16
  const int e  = blockIdx.z;   // 8
  const int t = threadIdx.x;
  const float* src = W + (((size_t)e * DIM) + (size_t)kb * 64) * DIM + nb * 64;
  #pragma unroll
  for (int p = 0; p < 4; ++p) {
    int q = p * 256 + t;       // 0..1023 float4-units
    int i = q >> 4;            // k-row 0..63
    int j4 = q & 15;           // float4 within row
    float4 v = *(const float4*)(src + (size_t)i * DIM + j4 * 4);
    tile[i][j4 * 4 + 0] = v.x; tile[i][j4 * 4 + 1] = v.y;
    tile[i][j4 * 4 + 2] = v.z; tile[i][j4 * 4 + 3] = v.w;
  }
  __syncthreads();
  unsigned short* dst = WT + (((size_t)e * DIM) + (size_t)nb * 64) * DIM + kb * 64;
  #pragma unroll
  for (int p = 0; p < 4; ++p) {
    int q = p * 256 + t;
    int j = q >> 4;            // n-row 0..63
    int i4 = q & 15;           // k float4
    ushort4 o;
    o.x = f2bf(tile[i4 * 4 + 0][j]);
    o.y = f2bf(tile[i4 * 4 + 1][j]);
    o.z = f2bf(tile[i4 * 4 + 2][j]);
    o.w = f2bf(tile[i4 * 4 + 3][j]);
    *(ushort4*)(dst + (size_t)j * DIM + i4 * 4) = o;
  }
}

// -- kernel 3: grouped GEMM, r7 geometry, EXPERT-ALIGNED tiles (uniform expert per tile) --
__global__ __launch_bounds__(256, 6) void k_moe_gemm(
    const unsigned short* __restrict__ xb,   // [N_TOK][DIM] bf16 (token order)
    const unsigned short* __restrict__ WT,   // [NEXP][DIM n][DIM k] bf16
    const int* __restrict__ sei, const int* __restrict__ ssi, const int* __restrict__ kp,
    const int* __restrict__ tbl,             // [MAXTILES][2] = {expert, row_start}
    const float* __restrict__ zbuf,
    unsigned short* __restrict__ outw)       // [NSORT][DIM] bf16, rows at flat-slot index
{
  __shared__ unsigned short lA[BM * BK];   // 16 KB
  __shared__ unsigned short lB[BN * BK];   // 8 KB
  __shared__ int s_sei[BM];
  __shared__ int s_ssi[BM];
  __shared__ int s_tok[BM];

  // XCD-aware bijective swizzle (nwg=1152, 1152%8==0): contiguous 144-chunk per XCD;
  // ct-fastest decode -> the 16 ct-blocks sharing one A row-panel stay in one XCD's L2.
  const int swz = (blockIdx.x & 7) * 144 + (blockIdx.x >> 3);
  const int rt = swz >> 4;             // 0..71 tile index
  const int ct = swz & 15;             // 0..15 col tile
  const int te = tbl[rt * 2 + 0];      // tile's expert (uniform); -1 = dead tile
  if (te < 0) return;
  const int r0 = tbl[rt * 2 + 1];      // first sorted row of this tile

  const int t = threadIdx.x;
  const int lane = t & 63;
  const int w = t >> 6;                // 4 waves, 2M x 2N (64x32 tile each)
  const int wr = w >> 1;
  const int wc = w & 1;
  const int kk = kp[0];

  if (t < BM) {
    int gr = r0 + t; if (gr > NSORT - 1) gr = NSORT - 1;   // clamp: duplicate rows benign
    const int si = ssi[gr];
    s_sei[t] = sei[gr];
    s_ssi[t] = si;
    s_tok[t] = si / kk;                // source token for A-row indirection
  }
  __syncthreads();

  f32x4 acc[4][2];
  #pragma unroll
  for (int m = 0; m < 4; ++m)
    #pragma unroll
    for (int n = 0; n < 2; ++n)
      acc[m][n] = (f32x4){0.f, 0.f, 0.f, 0.f};

  const int g = lane >> 4;
  const int r = lane & 15;

  // staging geometry (rule 21: linear LDS dest, inverse-swizzled global source)
  // A: 16 chunks of 1KB, wave owns 4w..4w+3;  B: 8 chunks, wave owns 2w..2w+1
  int rA[4], kA[4], rB[2], kB[2];
  #pragma unroll
  for (int i = 0; i < 4; ++i) {
    int o = (4 * w + i) * 1024 + lane * 16;
    int osw = o ^ (((o >> 7) & 7) << 4);
    rA[i] = osw >> 7; kA[i] = osw & 127;
  }
  #pragma unroll
  for (int i = 0; i < 2; ++i) {
    int o = (2 * w + i) * 1024 + lane * 16;
    int osw = o ^ (((o >> 7) & 7) << 4);
    rB[i] = osw >> 7; kB[i] = osw & 127;   // n-row 0..63
  }

  // hoisted source bases (ONCE — tile is single-expert); boundary rows -> zero page
  const char *ap[4], *bp[2];
  #pragma unroll
  for (int i = 0; i < 4; ++i)
    ap[i] = (s_sei[rA[i]] == te)
        ? (const char*)(xb + (size_t)s_tok[rA[i]] * DIM) + kA[i] : (const char*)zbuf;
  #pragma unroll
  for (int i = 0; i < 2; ++i)
    bp[i] = (const char*)(WT + (((size_t)te * DIM) + ct * BN + rB[i]) * DIM) + kB[i];

  #pragma unroll 1
  for (int s = 0; s < DIM / BK; ++s) {   // exactly 16 K-steps, single expert
    const int koff = s * 128;            // bytes along k (4KB zero page covers +kA+16)
    #pragma unroll
    for (int i = 0; i < 4; ++i)
      gload16((char*)lA + (4 * w + i) * 1024, ap[i] + koff);
    #pragma unroll
    for (int i = 0; i < 2; ++i)
      gload16((char*)lB + (2 * w + i) * 1024, bp[i] + koff);

    __syncthreads();   // vmcnt(0) drain + barrier
    #pragma unroll
    for (int kh = 0; kh < 2; ++kh) {
      const int kbyte = (kh * 32 + 8 * g) * 2;   // same k-slot for A and B (positional symmetry)
      bfrag af[4], bfv[2];
      #pragma unroll
      for (int m = 0; m < 4; ++m) {
        const int row = wr * 64 + m * 16 + r;
        int o = (row << 7) + kbyte;
        o ^= ((row & 7) << 4);
        af[m] = *(const bfrag*)((const char*)lA + o);
      }
      #pragma unroll
      for (int n = 0; n < 2; ++n) {
        const int nn = wc * 32 + n * 16 + r;
        int o = (nn << 7) + kbyte;
        o ^= ((nn & 7) << 4);
        bfv[n] = *(const bfrag*)((const char*)lB + o);
      }
      #pragma unroll
      for (int m = 0; m < 4; ++m)
        #pragma unroll
        for (int n = 0; n < 2; ++n)
          acc[m][n] = __builtin_amdgcn_mfma_f32_16x16x32_bf16(af[m], bfv[n], acc[m][n], 0, 0, 0);
    }
    __syncthreads();   // compute done before next stage overwrites LDS
  }

  // epilogue: C/D map col = lane&15, row = (lane>>4)*4 + reg; scatter rows by ssi (bf16);
  // skip rows belonging to the neighboring expert (they're covered by that expert's tile)
  #pragma unroll
  for (int m = 0; m < 4; ++m) {
    #pragma unroll
    for (int q = 0; q < 4; ++q) {
      const int rl = wr * 64 + m * 16 + g * 4 + q;
      if (s_sei[rl] != te) continue;
      const int orow = s_ssi[rl];
      unsigned short* od = outw + (size_t)orow * DIM + ct * BN + wc * 32 + r;
      #pragma unroll
      for (int n = 0; n < 2; ++n)
        od[n * 16] = f2bf(acc[m][n][q]);
    }
  }
}

// ---------------- kernel 4: gate-weighted pair combine -> fp32 out ----------------------
__global__ __launch_bounds__(256) void k_combine(
    const unsigned short* __restrict__ outw, const float* __restrict__ gates,
    const int* __restrict__ kp, float* __restrict__ out)
{
  const int tk = blockIdx.x;     // token
  const int t = threadIdx.x;     // 256 threads x 4 floats
  const int kk = kp[0];
  float4 o = {0.f, 0.f, 0.f, 0.f};
  for (int s = 0; s < kk; ++s) {
    const float gte = gates[tk * kk + s];
    ushort4 a = ((const ushort4*)(outw + ((size_t)tk * kk + s) * DIM))[t];
    o.x += gte * bf2f(a.x);
    o.y += gte * bf2f(a.y);
    o.z += gte * bf2f(a.z);
    o.w += gte * bf2f(a.w);
  }
  ((float4*)(out + (size_t)tk * DIM))[t] = o;
}

extern "C" void kernel_launch(void* const* d_in, const int* in_sizes, int n_in,
                              void* d_out, int out_size, void* d_ws, size_t ws_size,
                              hipStream_t stream)
{
  const float* x     = (const float*)d_in[0];
  const float* W     = (const float*)d_in[1];
  const float* gates = (const float*)d_in[2];
  const int* kp      = (const int*)d_in[3];
  const int* sei     = (const int*)d_in[4];
  const int* ssi     = (const int*)d_in[5];
  const int* eoff    = (const int*)d_in[7];   // expert_offsets (cumsum of counts)

  const size_t MB = 1024 * 1024;
  if (ws_size < 40 * MB + 8192) return;   // 40MB scratch + 4KB zero page + tile table

  char* ws = (char*)d_ws;
  unsigned short* xb   = (unsigned short*)(ws);              // 8  MB: bf16 x (token order)
  unsigned short* WT   = (unsigned short*)(ws + 8 * MB);     // 16 MB: bf16 W^T
  unsigned short* outw = (unsigned short*)(ws + 24 * MB);    // 16 MB: bf16 out_flat
  float* zbuf          = (float*)(ws + 40 * MB);             // 4 KB zero page
  int* tbl             = (int*)(ws + 40 * MB + 4096);        // 576 B tile table

  k_prep<<<N_TOK * DIM / (256 * 8), 256, 0, stream>>>(x, eoff, xb, zbuf, tbl);
  k_transp_w<<<dim3(16, 16, 8), 256, 0, stream>>>(W, WT);
  k_moe_gemm<<<MAXTILES * (DIM / BN), 256, 0, stream>>>(
      xb, WT, sei, ssi, kp, tbl, zbuf, outw);
  k_combine<<<N_TOK, 256, 0, stream>>>(outw, gates, kp, (float*)d_out);
}

// Round 18
// 51.691 us; speedup vs baseline: 1.2168x; 1.0501x over previous
//
#include <hip/hip_runtime.h>
#include <hip/hip_bf16.h>
#include <stdint.h>

#define N_TOK   4096
#define TOPK    2
#define NSORT   (N_TOK * TOPK)   // 8192
#define NEXP    8
#define DIM     1024

#define BM 128
#define BN 64
#define BK 64
#define MAXTILES 72              // sum_e ceil(cnt_e/128) <= 64 + 7; padded to 72

typedef __attribute__((ext_vector_type(8))) short bfrag;    // 8 bf16 = 4 VGPR (MFMA A/B operand)
typedef __attribute__((ext_vector_type(4))) float f32x4;    // MFMA C/D

static __device__ __forceinline__ unsigned short f2bf(float f) {
  __hip_bfloat16 h = __float2bfloat16(f);
  return __builtin_bit_cast(unsigned short, h);
}
static __device__ __forceinline__ float bf2f(unsigned short u) {
  unsigned int v = ((unsigned int)u) << 16;
  return __builtin_bit_cast(float, v);
}

// async global->LDS, 16B per lane; lds base must be wave-uniform (HW writes base + lane*16)
static __device__ __forceinline__ void gload16(void* lds_base, const void* gsrc) {
  __builtin_amdgcn_global_load_lds(
      (const __attribute__((address_space(1))) void*)gsrc,
      (__attribute__((address_space(3))) void*)lds_base, 16, 0, 0);
}

// -- kernel 1 (fused prepass): blocks 0..2047 transpose+cast W; blocks 2048..2559 cast x;
//    block 2048 also builds the zero page + expert-aligned tile table.
__global__ __launch_bounds__(256) void k_prep_w(
    const float* __restrict__ W, const float* __restrict__ x, const int* __restrict__ eoff,
    unsigned short* __restrict__ WT, unsigned short* __restrict__ xb,
    float* __restrict__ zbuf, int* __restrict__ tbl)
{
  const int b = blockIdx.x;
  const int t = threadIdx.x;

  if (b < 2048) {
    // ---- W [e][k][n] fp32 -> WT [e][n][k] bf16, 64x64 LDS-tiled transpose ----
    __shared__ float tile[64][65];
    const int e  = b >> 8;
    const int kb = (b >> 4) & 15;
    const int nb = b & 15;
    const float* src = W + (((size_t)e * DIM) + (size_t)kb * 64) * DIM + nb * 64;
    #pragma unroll
    for (int p = 0; p < 4; ++p) {
      int q = p * 256 + t;       // 0..1023 float4-units
      int i = q >> 4;            // k-row 0..63
      int j4 = q & 15;           // float4 within row
      float4 v = *(const float4*)(src + (size_t)i * DIM + j4 * 4);
      tile[i][j4 * 4 + 0] = v.x; tile[i][j4 * 4 + 1] = v.y;
      tile[i][j4 * 4 + 2] = v.z; tile[i][j4 * 4 + 3] = v.w;
    }
    __syncthreads();
    unsigned short* dst = WT + (((size_t)e * DIM) + (size_t)nb * 64) * DIM + kb * 64;
    #pragma unroll
    for (int p = 0; p < 4; ++p) {
      int q = p * 256 + t;
      int j = q >> 4;            // n-row 0..63
      int i4 = q & 15;           // k float4
      ushort4 o;
      o.x = f2bf(tile[i4 * 4 + 0][j]);
      o.y = f2bf(tile[i4 * 4 + 1][j]);
      o.z = f2bf(tile[i4 * 4 + 2][j]);
      o.w = f2bf(tile[i4 * 4 + 3][j]);
      *(ushort4*)(dst + (size_t)j * DIM + i4 * 4) = o;
    }
  } else {
    // ---- x fp32 -> bf16 (token order); 512 blocks x 4 iters x 8 floats/thread ----
    const int c = b - 2048;
    #pragma unroll
    for (int it = 0; it < 4; ++it) {
      const size_t i = ((size_t)c * 8192) + (size_t)it * 2048 + (size_t)t * 8;
      float4 a = *(const float4*)(x + i);
      float4 v = *(const float4*)(x + i + 4);
      ushort4 oa, ob;
      oa.x = f2bf(a.x); oa.y = f2bf(a.y); oa.z = f2bf(a.z); oa.w = f2bf(a.w);
      ob.x = f2bf(v.x); ob.y = f2bf(v.y); ob.z = f2bf(v.z); ob.w = f2bf(v.w);
      *(ushort4*)(xb + i) = oa;
      *(ushort4*)(xb + i + 4) = ob;
    }
    if (c == 0) {                              // 4KB zero page + tile table
      zbuf[t] = 0.f; zbuf[256 + t] = 0.f;
      zbuf[512 + t] = 0.f; zbuf[768 + t] = 0.f;
      if (t == 0) {
        int ti = 0, prev = 0;
        for (int e = 0; e < NEXP; ++e) {
          const int end = eoff[e];
          for (int r0 = prev; r0 < end; r0 += BM) {
            tbl[ti * 2 + 0] = e;
            tbl[ti * 2 + 1] = r0;
            ++ti;
          }
          prev = end;
        }
        for (; ti < MAXTILES; ++ti) { tbl[ti * 2 + 0] = -1; tbl[ti * 2 + 1] = 0; }
      }
    }
  }
}

// -- kernel 2: grouped GEMM, r7 geometry, EXPERT-ALIGNED tiles (uniform expert per tile) --
__global__ __launch_bounds__(256, 6) void k_moe_gemm(
    const unsigned short* __restrict__ xb,   // [N_TOK][DIM] bf16 (token order)
    const unsigned short* __restrict__ WT,   // [NEXP][DIM n][DIM k] bf16
    const int* __restrict__ sei, const int* __restrict__ ssi, const int* __restrict__ kp,
    const int* __restrict__ tbl,             // [MAXTILES][2] = {expert, row_start}
    const float* __restrict__ zbuf,
    unsigned short* __restrict__ outw)       // [NSORT][DIM] bf16, rows at flat-slot index
{
  __shared__ unsigned short lA[BM * BK];   // 16 KB
  __shared__ unsigned short lB[BN * BK];   // 8 KB
  __shared__ int s_sei[BM];
  __shared__ int s_ssi[BM];
  __shared__ int s_tok[BM];

  // XCD-aware bijective swizzle (nwg=1152, 1152%8==0): contiguous 144-chunk per XCD;
  // ct-fastest decode -> the 16 ct-blocks sharing one A row-panel stay in one XCD's L2.
  const int swz = (blockIdx.x & 7) * 144 + (blockIdx.x >> 3);
  const int rt = swz >> 4;             // 0..71 tile index
  const int ct = swz & 15;             // 0..15 col tile
  const int te = tbl[rt * 2 + 0];      // tile's expert (uniform); -1 = dead tile
  if (te < 0) return;
  const int r0 = tbl[rt * 2 + 1];      // first sorted row of this tile

  const int t = threadIdx.x;
  const int lane = t & 63;
  const int w = t >> 6;                // 4 waves, 2M x 2N (64x32 tile each)
  const int wr = w >> 1;
  const int wc = w & 1;
  const int kk = kp[0];

  if (t < BM) {
    int gr = r0 + t; if (gr > NSORT - 1) gr = NSORT - 1;   // clamp: duplicate rows benign
    const int si = ssi[gr];
    s_sei[t] = sei[gr];
    s_ssi[t] = si;
    s_tok[t] = si / kk;                // source token for A-row indirection
  }
  __syncthreads();

  f32x4 acc[4][2];
  #pragma unroll
  for (int m = 0; m < 4; ++m)
    #pragma unroll
    for (int n = 0; n < 2; ++n)
      acc[m][n] = (f32x4){0.f, 0.f, 0.f, 0.f};

  const int g = lane >> 4;
  const int r = lane & 15;

  // staging geometry (rule 21: linear LDS dest, inverse-swizzled global source)
  // A: 16 chunks of 1KB, wave owns 4w..4w+3;  B: 8 chunks, wave owns 2w..2w+1
  int rA[4], kA[4], rB[2], kB[2];
  #pragma unroll
  for (int i = 0; i < 4; ++i) {
    int o = (4 * w + i) * 1024 + lane * 16;
    int osw = o ^ (((o >> 7) & 7) << 4);
    rA[i] = osw >> 7; kA[i] = osw & 127;
  }
  #pragma unroll
  for (int i = 0; i < 2; ++i) {
    int o = (2 * w + i) * 1024 + lane * 16;
    int osw = o ^ (((o >> 7) & 7) << 4);
    rB[i] = osw >> 7; kB[i] = osw & 127;   // n-row 0..63
  }

  // hoisted source bases (ONCE — tile is single-expert); boundary rows -> zero page
  const char *ap[4], *bp[2];
  #pragma unroll
  for (int i = 0; i < 4; ++i)
    ap[i] = (s_sei[rA[i]] == te)
        ? (const char*)(xb + (size_t)s_tok[rA[i]] * DIM) + kA[i] : (const char*)zbuf;
  #pragma unroll
  for (int i = 0; i < 2; ++i)
    bp[i] = (const char*)(WT + (((size_t)te * DIM) + ct * BN + rB[i]) * DIM) + kB[i];

  #pragma unroll 1
  for (int s = 0; s < DIM / BK; ++s) {   // exactly 16 K-steps, single expert
    const int koff = s * 128;            // bytes along k (4KB zero page covers +kA+16)
    #pragma unroll
    for (int i = 0; i < 4; ++i)
      gload16((char*)lA + (4 * w + i) * 1024, ap[i] + koff);
    #pragma unroll
    for (int i = 0; i < 2; ++i)
      gload16((char*)lB + (2 * w + i) * 1024, bp[i] + koff);

    __syncthreads();   // vmcnt(0) drain + barrier
    #pragma unroll
    for (int kh = 0; kh < 2; ++kh) {
      const int kbyte = (kh * 32 + 8 * g) * 2;   // same k-slot for A and B (positional symmetry)
      bfrag af[4], bfv[2];
      #pragma unroll
      for (int m = 0; m < 4; ++m) {
        const int row = wr * 64 + m * 16 + r;
        int o = (row << 7) + kbyte;
        o ^= ((row & 7) << 4);
        af[m] = *(const bfrag*)((const char*)lA + o);
      }
      #pragma unroll
      for (int n = 0; n < 2; ++n) {
        const int nn = wc * 32 + n * 16 + r;
        int o = (nn << 7) + kbyte;
        o ^= ((nn & 7) << 4);
        bfv[n] = *(const bfrag*)((const char*)lB + o);
      }
      #pragma unroll
      for (int m = 0; m < 4; ++m)
        #pragma unroll
        for (int n = 0; n < 2; ++n)
          acc[m][n] = __builtin_amdgcn_mfma_f32_16x16x32_bf16(af[m], bfv[n], acc[m][n], 0, 0, 0);
    }
    __syncthreads();   // compute done before next stage overwrites LDS
  }

  // epilogue: C/D map col = lane&15, row = (lane>>4)*4 + reg; scatter rows by ssi (bf16);
  // skip rows belonging to the neighboring expert (they're covered by that expert's tile)
  #pragma unroll
  for (int m = 0; m < 4; ++m) {
    #pragma unroll
    for (int q = 0; q < 4; ++q) {
      const int rl = wr * 64 + m * 16 + g * 4 + q;
      if (s_sei[rl] != te) continue;
      const int orow = s_ssi[rl];
      unsigned short* od = outw + (size_t)orow * DIM + ct * BN + wc * 32 + r;
      #pragma unroll
      for (int n = 0; n < 2; ++n)
        od[n * 16] = f2bf(acc[m][n][q]);
    }
  }
}

// ---------------- kernel 3: gate-weighted pair combine -> fp32 out ----------------------
__global__ __launch_bounds__(256) void k_combine(
    const unsigned short* __restrict__ outw, const float* __restrict__ gates,
    const int* __restrict__ kp, float* __restrict__ out)
{
  const int tk = blockIdx.x;     // token
  const int t = threadIdx.x;     // 256 threads x 4 floats
  const int kk = kp[0];
  float4 o = {0.f, 0.f, 0.f, 0.f};
  for (int s = 0; s < kk; ++s) {
    const float gte = gates[tk * kk + s];
    ushort4 a = ((const ushort4*)(outw + ((size_t)tk * kk + s) * DIM))[t];
    o.x += gte * bf2f(a.x);
    o.y += gte * bf2f(a.y);
    o.z += gte * bf2f(a.z);
    o.w += gte * bf2f(a.w);
  }
  ((float4*)(out + (size_t)tk * DIM))[t] = o;
}

extern "C" void kernel_launch(void* const* d_in, const int* in_sizes, int n_in,
                              void* d_out, int out_size, void* d_ws, size_t ws_size,
                              hipStream_t stream)
{
  const float* x     = (const float*)d_in[0];
  const float* W     = (const float*)d_in[1];
  const float* gates = (const float*)d_in[2];
  const int* kp      = (const int*)d_in[3];
  const int* sei     = (const int*)d_in[4];
  const int* ssi     = (const int*)d_in[5];
  const int* eoff    = (const int*)d_in[7];   // expert_offsets (cumsum of counts)

  const size_t MB = 1024 * 1024;
  if (ws_size < 40 * MB + 8192) return;   // 40MB scratch + 4KB zero page + tile table

  char* ws = (char*)d_ws;
  unsigned short* xb   = (unsigned short*)(ws);              // 8  MB: bf16 x (token order)
  unsigned short* WT   = (unsigned short*)(ws + 8 * MB);     // 16 MB: bf16 W^T
  unsigned short* outw = (unsigned short*)(ws + 24 * MB);    // 16 MB: bf16 out_flat
  float* zbuf          = (float*)(ws + 40 * MB);             // 4 KB zero page
  int* tbl             = (int*)(ws + 40 * MB + 4096);        // 576 B tile table

  k_prep_w<<<2560, 256, 0, stream>>>(W, x, eoff, WT, xb, zbuf, tbl);
  k_moe_gemm<<<MAXTILES * (DIM / BN), 256, 0, stream>>>(
      xb, WT, sei, ssi, kp, tbl, zbuf, outw);
  k_combine<<<N_TOK, 256, 0, stream>>>(outw, gates, kp, (float*)d_out);
}